// Round 8
// baseline (274.485 us; speedup 1.0000x reference)
//
#include <hip/hip_runtime.h>

#define BB 64
#define SS 512
#define HH 768
#define EE 128
#define TT 4
#define H4 (HH / 4)        // 192 float4 lanes per row
#define NP (EE * TT)       // 512 (entity,token) pairs
#define NTYPES 5
#define BGRP 16            // batch rows per block
#define NBG (BB / BGRP)    // 4
#define NEBLK (SS * NBG)   // 2048 enhance tasks
#define NGBLK (EE * NBG)   // 512 gather tasks
#define SLOTS (H4 / BGRP)  // 12 prologue slots per batch-lane

// ---------------------------------------------------------------------------
// Kernel A: counting-sort ent_tokens (512 pairs) by token position s.
// ---------------------------------------------------------------------------
__global__ __launch_bounds__(SS) void build_index_kernel(
    const int* __restrict__ ent_tokens,
    int* __restrict__ offsets,    // S+1 ints
    int* __restrict__ entries) {  // E*T ints
  __shared__ int cnt[SS];
  __shared__ int scan[SS];
  __shared__ int pos[SS];
  const int tid = threadIdx.x;

  cnt[tid] = 0;
  __syncthreads();
  const int s = ent_tokens[tid];
  atomicAdd(&cnt[s], 1);
  __syncthreads();

  scan[tid] = cnt[tid];
  __syncthreads();
  for (int off = 1; off < SS; off <<= 1) {
    int add = (tid >= off) ? scan[tid - off] : 0;
    __syncthreads();
    scan[tid] += add;
    __syncthreads();
  }

  const int excl = scan[tid] - cnt[tid];
  offsets[tid] = excl;
  if (tid == 0) offsets[SS] = NP;
  pos[tid] = excl;
  __syncthreads();
  const int p = atomicAdd(&pos[s], 1);
  entries[p] = tid >> 2;
}

// ---------------------------------------------------------------------------
// Kernel B. Role by blk%5 (perfect CU-level role mix): %5<4 -> enhance task
// ((blk/5)*4 + blk%5), %5==4 -> gather task (blk/5).
// Enhance task (s, 16 b's): PROLOGUE resolves every correction into 6 scalars
// per b (5 weighted type-counts + conf-sum) via one parallel LDS pass; the
// STREAM is then a pure copy loop -- load row, 7 reg/LDS-broadcast FMAs per
// component, store -- depth-2 prefetch, no scalar chains, no branches
// (n==0 rows add exact 0). This is structurally the 6.4 TB/s fill/copy
// pattern: waves never stop issuing HBM loads.
// Gather task (e, 16 b's): same prologue trick over the entity's 4 buckets;
// stream does 4 L3-hit row loads + store per b.
// ---------------------------------------------------------------------------
__global__ __launch_bounds__(H4, 6) void fused_kernel(
    const float* __restrict__ hidden,
    const int* __restrict__ entity_types,   // (B,E)
    const float* __restrict__ conf,         // (B,E)
    const int* __restrict__ ent_tokens,     // (E,T)
    const float* __restrict__ type_table,   // (5,H)
    const float* __restrict__ conf_w,       // (H)
    const float* __restrict__ conf_b,       // (H)
    const int* __restrict__ offsets,
    const int* __restrict__ entries,
    float* __restrict__ enhanced,           // (B,S,H)
    float* __restrict__ ee) {               // (B,E,H)
  const int tid = threadIdx.x;  // 0..191
  const int u = blockIdx.x;
  const int r5 = u % 5;
  const int q5 = u / 5;

  __shared__ int scnt[BGRP][NTYPES];  // occurrence counts per (b-lane, type)
  __shared__ float scsum[BGRP];       // conf sums per b-lane
  if (tid < BGRP * NTYPES) scnt[tid / NTYPES][tid % NTYPES] = 0;
  if (tid < BGRP) scsum[tid] = 0.f;
  __syncthreads();

  const float4* tt4 = (const float4*)type_table;
  const float4* hp = (const float4*)hidden;
  const float4 wv = ((const float4*)conf_w)[tid];
  const float4 bv = ((const float4*)conf_b)[tid];
  const int bl = tid & (BGRP - 1);

  if (r5 < 4) {
    // ------------------------- enhance path -------------------------------
    const int eid = q5 * 4 + r5;          // 0..2047
    const int s = eid & (SS - 1);
    const int b0 = (eid >> 9) * BGRP;

    const int o0 = offsets[s];
    const int o1 = offsets[s + 1];
    const int n = o1 - o0;

    // prologue: all (entry, b) pairs resolved in parallel, no chains
    for (int slot = tid >> 4; slot < n; slot += SLOTS) {
      const int e = entries[o0 + slot];
      const int b = b0 + bl;
      atomicAdd(&scnt[bl][entity_types[b * EE + e]], 1);
      atomicAdd(&scsum[bl], conf[b * EE + e]);
    }
    __syncthreads();

    const float4 t0 = tt4[0 * H4 + tid];
    const float4 t1 = tt4[1 * H4 + tid];
    const float4 t2 = tt4[2 * H4 + tid];
    const float4 t3 = tt4[3 * H4 + tid];
    const float4 t4 = tt4[4 * H4 + tid];
    const float fn = (float)n;

    float4* outp = (float4*)enhanced;
    size_t idx = ((size_t)(b0 * SS + s)) * H4 + tid;
    const size_t step = (size_t)SS * H4;

    float4 cur = hp[idx];
#pragma unroll
    for (int i = 0; i < BGRP; ++i) {
      const float4 nxt = (i + 1 < BGRP) ? hp[idx + step] : cur;
      const float c0 = (float)scnt[i][0];
      const float c1 = (float)scnt[i][1];
      const float c2 = (float)scnt[i][2];
      const float c3 = (float)scnt[i][3];
      const float c4 = (float)scnt[i][4];
      const float cs = scsum[i];
      float4 v;
      v.x = fmaf(c0, t0.x, cur.x); v.y = fmaf(c0, t0.y, cur.y);
      v.z = fmaf(c0, t0.z, cur.z); v.w = fmaf(c0, t0.w, cur.w);
      v.x = fmaf(c1, t1.x, v.x);   v.y = fmaf(c1, t1.y, v.y);
      v.z = fmaf(c1, t1.z, v.z);   v.w = fmaf(c1, t1.w, v.w);
      v.x = fmaf(c2, t2.x, v.x);   v.y = fmaf(c2, t2.y, v.y);
      v.z = fmaf(c2, t2.z, v.z);   v.w = fmaf(c2, t2.w, v.w);
      v.x = fmaf(c3, t3.x, v.x);   v.y = fmaf(c3, t3.y, v.y);
      v.z = fmaf(c3, t3.z, v.z);   v.w = fmaf(c3, t3.w, v.w);
      v.x = fmaf(c4, t4.x, v.x);   v.y = fmaf(c4, t4.y, v.y);
      v.z = fmaf(c4, t4.z, v.z);   v.w = fmaf(c4, t4.w, v.w);
      v.x = fmaf(cs, wv.x, v.x);   v.y = fmaf(cs, wv.y, v.y);
      v.z = fmaf(cs, wv.z, v.z);   v.w = fmaf(cs, wv.w, v.w);
      v.x = fmaf(fn, bv.x, v.x);   v.y = fmaf(fn, bv.y, v.y);
      v.z = fmaf(fn, bv.z, v.z);   v.w = fmaf(fn, bv.w, v.w);
      outp[idx] = v;
      idx += step;
      cur = nxt;
    }
  } else {
    // ------------------------ gather/mean path ----------------------------
    const int gid = q5;                   // 0..511
    const int e = gid & (EE - 1);
    const int b0 = (gid >> 7) * BGRP;

    const int s0 = ent_tokens[e * TT + 0];
    const int s1 = ent_tokens[e * TT + 1];
    const int s2 = ent_tokens[e * TT + 2];
    const int s3 = ent_tokens[e * TT + 3];

    const int oA = offsets[s0], nA = offsets[s0 + 1] - oA;
    const int oB = offsets[s1], nB = offsets[s1 + 1] - oB;
    const int oC = offsets[s2], nC = offsets[s2 + 1] - oC;
    const int oD = offsets[s3], nD = offsets[s3 + 1] - oD;
    const int p1 = nA, p2 = nA + nB, p3 = nA + nB + nC;
    const int ntot = p3 + nD;

    // prologue: concatenated buckets; duplicates across buckets accumulate,
    // reproducing exactly the per-pair multiplicity of the reference
    for (int slot = tid >> 4; slot < ntot; slot += SLOTS) {
      int j;
      if (slot < p1)      j = oA + slot;
      else if (slot < p2) j = oB + (slot - p1);
      else if (slot < p3) j = oC + (slot - p2);
      else                j = oD + (slot - p3);
      const int e2 = entries[j];
      const int b = b0 + bl;
      atomicAdd(&scnt[bl][entity_types[b * EE + e2]], 1);
      atomicAdd(&scsum[bl], conf[b * EE + e2]);
    }
    __syncthreads();

    const float4 t0 = tt4[0 * H4 + tid];
    const float4 t1 = tt4[1 * H4 + tid];
    const float4 t2 = tt4[2 * H4 + tid];
    const float4 t3 = tt4[3 * H4 + tid];
    const float4 t4 = tt4[4 * H4 + tid];
    const float fn = (float)ntot;

    float4* eep = (float4*)ee;
#pragma unroll 2
    for (int i = 0; i < BGRP; ++i) {
      const int b = b0 + i;
      const float4* hb = hp + (size_t)b * SS * H4;
      const float4 v0 = hb[(size_t)s0 * H4 + tid];
      const float4 v1 = hb[(size_t)s1 * H4 + tid];
      const float4 v2 = hb[(size_t)s2 * H4 + tid];
      const float4 v3 = hb[(size_t)s3 * H4 + tid];
      const float c0 = (float)scnt[i][0];
      const float c1 = (float)scnt[i][1];
      const float c2 = (float)scnt[i][2];
      const float c3 = (float)scnt[i][3];
      const float c4 = (float)scnt[i][4];
      const float cs = scsum[i];
      float4 a;
      a.x = (v0.x + v1.x) + (v2.x + v3.x);
      a.y = (v0.y + v1.y) + (v2.y + v3.y);
      a.z = (v0.z + v1.z) + (v2.z + v3.z);
      a.w = (v0.w + v1.w) + (v2.w + v3.w);
      a.x = fmaf(c0, t0.x, a.x); a.y = fmaf(c0, t0.y, a.y);
      a.z = fmaf(c0, t0.z, a.z); a.w = fmaf(c0, t0.w, a.w);
      a.x = fmaf(c1, t1.x, a.x); a.y = fmaf(c1, t1.y, a.y);
      a.z = fmaf(c1, t1.z, a.z); a.w = fmaf(c1, t1.w, a.w);
      a.x = fmaf(c2, t2.x, a.x); a.y = fmaf(c2, t2.y, a.y);
      a.z = fmaf(c2, t2.z, a.z); a.w = fmaf(c2, t2.w, a.w);
      a.x = fmaf(c3, t3.x, a.x); a.y = fmaf(c3, t3.y, a.y);
      a.z = fmaf(c3, t3.z, a.z); a.w = fmaf(c3, t3.w, a.w);
      a.x = fmaf(c4, t4.x, a.x); a.y = fmaf(c4, t4.y, a.y);
      a.z = fmaf(c4, t4.z, a.z); a.w = fmaf(c4, t4.w, a.w);
      a.x = fmaf(cs, wv.x, a.x); a.y = fmaf(cs, wv.y, a.y);
      a.z = fmaf(cs, wv.z, a.z); a.w = fmaf(cs, wv.w, a.w);
      a.x = fmaf(fn, bv.x, a.x); a.y = fmaf(fn, bv.y, a.y);
      a.z = fmaf(fn, bv.z, a.z); a.w = fmaf(fn, bv.w, a.w);
      float4 o;
      o.x = 0.25f * a.x;
      o.y = 0.25f * a.y;
      o.z = 0.25f * a.z;
      o.w = 0.25f * a.w;
      eep[(size_t)(b * EE + e) * H4 + tid] = o;
    }
  }
}

extern "C" void kernel_launch(void* const* d_in, const int* in_sizes, int n_in,
                              void* d_out, int out_size, void* d_ws,
                              size_t ws_size, hipStream_t stream) {
  const float* hidden = (const float*)d_in[0];      // (B,S,H) fp32
  const int* entity_types = (const int*)d_in[1];    // (B,E) i32
  const float* conf = (const float*)d_in[2];        // (B,E) fp32
  const int* ent_tokens = (const int*)d_in[3];      // (E,T) i32
  const float* type_table = (const float*)d_in[4];  // (5,H) fp32
  const float* conf_w = (const float*)d_in[5];      // (1,H) fp32
  const float* conf_b = (const float*)d_in[6];      // (H) fp32

  float* enhanced = (float*)d_out;                   // (B,S,H)
  float* ee = (float*)d_out + (size_t)BB * SS * HH;  // (B,E,H)

  int* offsets = (int*)d_ws;          // S+1
  int* entries = offsets + (SS + 1);  // E*T

  build_index_kernel<<<1, SS, 0, stream>>>(ent_tokens, offsets, entries);
  fused_kernel<<<NEBLK + NGBLK, H4, 0, stream>>>(
      hidden, entity_types, conf, ent_tokens, type_table, conf_w, conf_b,
      offsets, entries, enhanced, ee);
}